// Round 5
// baseline (268.261 us; speedup 1.0000x reference)
//
#include <hip/hip_runtime.h>

// ---------------------------------------------------------------------------
// Attention (B=4, N=2048, DIM=1024, H=16, Dh=64) in fp16 MFMA, fp32 accum.
// Pipeline: prep (cast + 2 transposes fused) -> qkv_gemm (scatter epi)
//           -> flash attn -> out_gemm (bias epi).
// R12 (resubmit; R4 bench was an infra container failure, not a kernel
//   failure): qkv gemm wave-tile intensity fix. LDS-read bytes/FLOP for wave
//   tile MwxNw = (Mw+Nw)/(Mw*Nw); 64x64 (=1/32) needs 127 B/cyc/CU to feed
//   MFMA = the LDS roof -> R0/R11 stuck at ~640 TF regardless of staging
//   schedule. New qkv: block 256x128, 4 waves of 128x64 (1/42.7 -> ~93
//   B/cyc), BK=32, 3-buf counted-vmcnt rotation, 72KB LDS -> 2 blocks/CU,
//   grid 768. out_gemm keeps 128^2 3-buf (grid 512, 3/CU). attn frozen
//   (78.6us, setprio pinned as a win in R11).
// ---------------------------------------------------------------------------

typedef _Float16 half8 __attribute__((ext_vector_type(8)));
typedef __fp16 fp16v2 __attribute__((ext_vector_type(2)));
typedef float floatx4 __attribute__((ext_vector_type(4)));
typedef unsigned short u16;

struct __align__(8) U16x4 { u16 x, y, z, w; };

__device__ __forceinline__ u16 f2h(float f) {
  union { _Float16 h; u16 u; } cv;
  cv.h = (_Float16)f;
  return cv.u;
}

// async global->LDS, 16B per lane. LDS dest = wave-uniform base + lane*16.
__device__ __forceinline__ void g2l16(const void* g, void* l) {
  __builtin_amdgcn_global_load_lds(
      (const __attribute__((address_space(1))) void*)g,
      (__attribute__((address_space(3))) void*)l, 16, 0, 0);
}

// 2-bit chunk swizzle (4 chunks/row): slot c, row=c>>2 -> chunk^((row>>1)&3)
__device__ __forceinline__ int swz(int c) { return (c & 3) ^ ((c >> 3) & 3); }

// ---------------------------------------------------------------------------
// Kernel 1: fused prep. Blocks [0,4096): flat cast x fp32->fp16.
// Blocks [4096,4864): transpose+cast Wqkv [1024][3072] -> [3072][1024].
// Blocks [4864,5120): transpose+cast Wout [1024][1024] -> [1024][1024].
// ---------------------------------------------------------------------------
__global__ __launch_bounds__(256) void prep(const float* __restrict__ x,
                                            u16* __restrict__ Xh,
                                            const float* __restrict__ Wqkv,
                                            u16* __restrict__ Wqkvt,
                                            const float* __restrict__ Wout,
                                            u16* __restrict__ Woutt) {
  __shared__ u16 ls[64][72];
  const int bid = blockIdx.x;
  const int tid = threadIdx.x;
  if (bid < 4096) {
    long long base = ((long long)bid * 256 + tid) * 8;
    float4 a = *(const float4*)(x + base);
    float4 b = *(const float4*)(x + base + 4);
    U16x4 u0 = {f2h(a.x), f2h(a.y), f2h(a.z), f2h(a.w)};
    U16x4 u1 = {f2h(b.x), f2h(b.y), f2h(b.z), f2h(b.w)};
    *(U16x4*)(Xh + base) = u0;
    *(U16x4*)(Xh + base + 4) = u1;
    return;
  }
  const float* in;
  u16* out;
  int N, tile;
  if (bid < 4096 + 768) { in = Wqkv; out = Wqkvt; N = 3072; tile = bid - 4096; }
  else                  { in = Wout; out = Woutt; N = 1024; tile = bid - 4864; }
  const int K = 1024, nTK = 16;
  const int tk = tile % nTK, tn = tile / nTK;
#pragma unroll
  for (int i = 0; i < 4; ++i) {
    int idx = i * 256 + tid;
    int r = idx >> 4, c4 = (idx & 15) * 4;
    float4 v = *(const float4*)(in + (long long)(tk * 64 + r) * N + tn * 64 + c4);
    ls[r][c4 + 0] = f2h(v.x);
    ls[r][c4 + 1] = f2h(v.y);
    ls[r][c4 + 2] = f2h(v.z);
    ls[r][c4 + 3] = f2h(v.w);
  }
  __syncthreads();
#pragma unroll
  for (int i = 0; i < 4; ++i) {
    int idx = i * 256 + tid;
    int nr = idx >> 4, kc4 = (idx & 15) * 4;
    U16x4 u = {ls[kc4 + 0][nr], ls[kc4 + 1][nr], ls[kc4 + 2][nr], ls[kc4 + 3][nr]};
    *(U16x4*)(out + (long long)(tn * 64 + nr) * K + tk * 64 + kc4) = u;
  }
}

// ---------------------------------------------------------------------------
// Kernel 2: qkv GEMM. C[8192,3072] = Xh[8192,1024] @ Wqkvt[3072,1024]^T.
//   Block 256x128, 4 waves (2Mx2N) of 128x64 each. BK=32, 32 KT.
//   LDS: lsA 3 bufs x 256x32 (48KB), lsB 3 bufs x 128x32 (24KB) -> 72KB,
//   2 blocks/CU. Per KT t: read bf[4]+af[4] (XOR chunk swizzle, 2-way);
//   stage KT t+2 (6 g2l16/thread) into buf (cur+2)%3; barrier; lgkm(0);
//   16 MFMA (m-half 0); read ag[4] (m-half 1 rows); 16 MFMA; vmcnt(6)
//   [t<30] / vmcnt(0) [t==30]; barrier. Queue never drains mid-loop.
//   Scatter epilogue: Q (pre-scaled), K, V^T. Grid 768 (32 bm x 24 bn).
// ---------------------------------------------------------------------------
__global__ __launch_bounds__(256, 2) void qkv_gemm(const u16* __restrict__ A,
                                                   const u16* __restrict__ Bt,
                                                   u16* __restrict__ O0,
                                                   u16* __restrict__ O1,
                                                   u16* __restrict__ O2) {
  __shared__ __attribute__((aligned(16))) u16 lsA[3 * 8192];  // 48KB
  __shared__ __attribute__((aligned(16))) u16 lsB[3 * 4096];  // 24KB
  const int tid = threadIdx.x;
  const int lane = tid & 63, wave = tid >> 6;
  const int l15 = lane & 15, quad = lane >> 4;
  const int rdoff = (quad ^ ((l15 >> 1) & 3)) * 8;  // read-side chunk swizzle
  const int wm = (wave >> 1) * 128, wn = (wave & 1) * 64;
  const int b = (blockIdx.x & 7) * 96 + (blockIdx.x >> 3);  // XCD, 768%8==0
  const int bm = b & 31, bn = b >> 5;

  // staging: slot sl covers (row r, chunk cc); source chunk pre-swizzled so
  // linear LDS write + swizzled read match.
  const u16* gA[4];
  const u16* gB[2];
  int dA[4], dB[2];
#pragma unroll
  for (int j = 0; j < 4; ++j) {
    int sl = j * 256 + tid;
    int r = sl >> 2, cc = sl & 3;
    gA[j] = A + (long long)(bm * 256 + r) * 1024 + (cc ^ ((r >> 1) & 3)) * 8;
    dA[j] = sl * 8;
  }
#pragma unroll
  for (int j = 0; j < 2; ++j) {
    int sl = j * 256 + tid;
    int r = sl >> 2, cc = sl & 3;
    gB[j] = Bt + (long long)(bn * 128 + r) * 1024 + (cc ^ ((r >> 1) & 3)) * 8;
    dB[j] = sl * 8;
  }

  floatx4 acc[8][4] = {};

  // ---- prologue: stage KT0 -> buf0, KT1 -> buf1 (12 loads/thread) ----
#pragma unroll
  for (int t = 0; t < 2; ++t) {
#pragma unroll
    for (int j = 0; j < 4; ++j) g2l16(gA[j] + t * 32, lsA + t * 8192 + dA[j]);
#pragma unroll
    for (int j = 0; j < 2; ++j) g2l16(gB[j] + t * 32, lsB + t * 4096 + dB[j]);
  }
  asm volatile("s_waitcnt vmcnt(6)");  // KT0 landed; KT1 in flight
  __builtin_amdgcn_s_barrier();

  int cur = 0;
  for (int t = 0; t < 32; ++t) {
    const u16* bA = lsA + cur * 8192;
    const u16* bB = lsB + cur * 4096;
    half8 af[4], bf[4];
#pragma unroll
    for (int i = 0; i < 4; ++i)
      bf[i] = *(const half8*)(bB + (wn + i * 16 + l15) * 32 + rdoff);
#pragma unroll
    for (int i = 0; i < 4; ++i)
      af[i] = *(const half8*)(bA + (wm + i * 16 + l15) * 32 + rdoff);
    if (t < 30) {  // stage KT t+2 into buf (cur+2)%3
      const int nb = cur ? cur - 1 : 2;
      const int ko = (t + 2) * 32;
#pragma unroll
      for (int j = 0; j < 4; ++j) g2l16(gA[j] + ko, lsA + nb * 8192 + dA[j]);
#pragma unroll
      for (int j = 0; j < 2; ++j) g2l16(gB[j] + ko, lsB + nb * 4096 + dB[j]);
    }
    __builtin_amdgcn_s_barrier();
    asm volatile("s_waitcnt lgkmcnt(0)");
#pragma unroll
    for (int i = 0; i < 4; ++i)
#pragma unroll
      for (int nt = 0; nt < 4; ++nt)
        acc[i][nt] = __builtin_amdgcn_mfma_f32_16x16x32_f16(af[i], bf[nt],
                                                            acc[i][nt], 0, 0, 0);
    half8 ag[4];
#pragma unroll
    for (int i = 0; i < 4; ++i)
      ag[i] = *(const half8*)(bA + (wm + 64 + i * 16 + l15) * 32 + rdoff);
#pragma unroll
    for (int i = 0; i < 4; ++i)
#pragma unroll
      for (int nt = 0; nt < 4; ++nt)
        acc[4 + i][nt] = __builtin_amdgcn_mfma_f32_16x16x32_f16(ag[i], bf[nt],
                                                                acc[4 + i][nt], 0, 0, 0);
    if (t < 30)       asm volatile("s_waitcnt vmcnt(6)");  // KT t+1 landed
    else if (t == 30) asm volatile("s_waitcnt vmcnt(0)");  // KT31 landed
    __builtin_amdgcn_s_barrier();
    cur = cur == 2 ? 0 : cur + 1;
  }

  // ---- scatter epilogue: Q (pre-scaled by SCALE*log2e), K, V^T ----
  const float slq = 0.125f * 1.44269504088896f;
#pragma unroll
  for (int mt = 0; mt < 8; ++mt) {
    int gm = bm * 256 + wm + (mt >> 2) * 64 + (mt & 3) * 16 + quad * 4;
    int bb = gm >> 11, n0 = gm & 2047;
#pragma unroll
    for (int nt = 0; nt < 4; ++nt) {
      int gc = bn * 128 + wn + nt * 16 + l15;
      int tsel = gc >> 10, hd = gc & 1023, h = hd >> 6, d = hd & 63;
      long long bh = (long long)(bb * 16 + h);
      if (tsel == 2) {
        U16x4 u = {f2h(acc[mt][nt][0]), f2h(acc[mt][nt][1]),
                   f2h(acc[mt][nt][2]), f2h(acc[mt][nt][3])};
        *(U16x4*)(O2 + (bh * 64 + d) * 2048 + n0) = u;
      } else {
        float s = (tsel == 0) ? slq : 1.0f;
        u16* dstp = (tsel == 0 ? O0 : O1) + (bh * 2048 + n0) * 64 + d;
#pragma unroll
        for (int r = 0; r < 4; ++r) dstp[r * 64] = f2h(acc[mt][nt][r] * s);
      }
    }
  }
}

// ---------------------------------------------------------------------------
// Kernel 4: out-proj GEMM + bias (R11 gemm_f16<1> body). 128x128 tile,
// BK=32, 4 waves of 64x64, 3-buf counted vmcnt(4), 48KB -> 3 blocks/CU,
// grid 512.
// ---------------------------------------------------------------------------
__global__ __launch_bounds__(256, 3) void out_gemm(const u16* __restrict__ A,
                                                   const u16* __restrict__ Bt,
                                                   float* __restrict__ Of,
                                                   const float* __restrict__ bias) {
  __shared__ __attribute__((aligned(16))) u16 lsA[3 * 4096];  // 24KB
  __shared__ __attribute__((aligned(16))) u16 lsB[3 * 4096];  // 24KB
  const int tid = threadIdx.x;
  const int lane = tid & 63, wave = tid >> 6;
  const int l15 = lane & 15, quad = lane >> 4;
  const int rdoff = (quad ^ ((l15 >> 1) & 3)) * 8;
  const int wm = (wave >> 1) * 64, wn = (wave & 1) * 64;
  const int bm = blockIdx.x & 63, bn = blockIdx.x >> 6;

  const u16* gA[2];
  const u16* gB[2];
  int dst[2];
#pragma unroll
  for (int j = 0; j < 2; ++j) {
    int sl = j * 256 + tid;
    int r = sl >> 2, cc = sl & 3;
    int csw = (cc ^ ((r >> 1) & 3)) * 8;
    gA[j] = A + (long long)(bm * 128 + r) * 1024 + csw;
    gB[j] = Bt + (long long)(bn * 128 + r) * 1024 + csw;
    dst[j] = sl * 8;
  }

  floatx4 acc[4][4] = {};

#pragma unroll
  for (int t = 0; t < 2; ++t) {
#pragma unroll
    for (int j = 0; j < 2; ++j) g2l16(gA[j] + t * 32, lsA + t * 4096 + dst[j]);
#pragma unroll
    for (int j = 0; j < 2; ++j) g2l16(gB[j] + t * 32, lsB + t * 4096 + dst[j]);
  }
  asm volatile("s_waitcnt vmcnt(4)");
  __builtin_amdgcn_s_barrier();

  int cur = 0;
  for (int t = 0; t < 32; ++t) {
    const u16* bA = lsA + cur * 4096;
    const u16* bB = lsB + cur * 4096;
    half8 af[4], bf[4];
#pragma unroll
    for (int i = 0; i < 4; ++i)
      af[i] = *(const half8*)(bA + (wm + i * 16 + l15) * 32 + rdoff);
#pragma unroll
    for (int i = 0; i < 4; ++i)
      bf[i] = *(const half8*)(bB + (wn + i * 16 + l15) * 32 + rdoff);
    if (t < 30) {
      const int nb = cur ? cur - 1 : 2;
      const int ko = (t + 2) * 32;
#pragma unroll
      for (int j = 0; j < 2; ++j) g2l16(gA[j] + ko, lsA + nb * 4096 + dst[j]);
#pragma unroll
      for (int j = 0; j < 2; ++j) g2l16(gB[j] + ko, lsB + nb * 4096 + dst[j]);
    }
    __builtin_amdgcn_s_barrier();
    asm volatile("s_waitcnt lgkmcnt(0)");
#pragma unroll
    for (int mt = 0; mt < 4; ++mt)
#pragma unroll
      for (int nt = 0; nt < 4; ++nt)
        acc[mt][nt] = __builtin_amdgcn_mfma_f32_16x16x32_f16(af[mt], bf[nt],
                                                             acc[mt][nt], 0, 0, 0);
    if (t < 30)       asm volatile("s_waitcnt vmcnt(4)");
    else if (t == 30) asm volatile("s_waitcnt vmcnt(0)");
    __builtin_amdgcn_s_barrier();
    cur = cur == 2 ? 0 : cur + 1;
  }

#pragma unroll
  for (int mt = 0; mt < 4; ++mt) {
    int gm = bm * 128 + wm + mt * 16 + quad * 4;
#pragma unroll
    for (int nt = 0; nt < 4; ++nt) {
      int gc = bn * 128 + wn + nt * 16 + l15;
      float bv = bias[gc];
#pragma unroll
      for (int r = 0; r < 4; ++r)
        Of[(long long)(gm + r) * 1024 + gc] = acc[mt][nt][r] + bv;
    }
  }
}

// ---------------------------------------------------------------------------
// Kernel 3: flash attention (R11 body, 78.6us measured; setprio pinned).
// Wave owns 64 q, q-tile 256/block, grid 512. Double-buffered 64-key K/V
// tiles, one barrier/iter, S^T formulation, no-shift softmax, MFMA row-sums.
// ---------------------------------------------------------------------------
__global__ __launch_bounds__(256, 2) void attn_flash(const u16* __restrict__ Qh,
                                                     const u16* __restrict__ Kh,
                                                     const u16* __restrict__ Vt,
                                                     u16* __restrict__ Oh) {
  __shared__ __attribute__((aligned(16))) u16 lsK[2 * 2 * 64 * 32];
  __shared__ __attribute__((aligned(16))) u16 lsV[2 * 2 * 64 * 32];
  __shared__ __attribute__((aligned(16))) u16 lsP[4 * 64 * 32];
  const int tid = threadIdx.x;
  const int lane = tid & 63, wave = tid >> 6;
  const int l15 = lane & 15, quad = lane >> 4;
  const int sw = (l15 >> 1) & 3;
  const int qsw8 = (quad ^ sw) * 8;
  const int bh = blockIdx.x & 63, qt = blockIdx.x >> 6;  // qt in [0,8)
  const u16* Qb = Qh + ((long long)bh * 2048 + qt * 256) * 64;
  const u16* Kb = Kh + (long long)bh * 2048 * 64;
  const u16* Vb = Vt + (long long)bh * 64 * 2048;
  u16* lsPw = lsP + wave * 2048;

  // ---- stage Q in two 128-row passes via lsK [2 dslab][128 row][32] ----
  half8 qb[4][2];  // [qt2][dslab]
#pragma unroll
  for (int pass = 0; pass < 2; ++pass) {
#pragma unroll
    for (int i = 0; i < 4; ++i) {
      int c = i * 256 + tid;
      g2l16(Qb + (pass * 128 + ((c >> 2) & 127)) * 64 + (c >> 9) * 32 + swz(c) * 8,
            lsK + (i * 256 + wave * 64) * 8);
    }
    __syncthreads();
    if ((wave >> 1) == pass) {
      const int lrow = (wave & 1) * 64;
#pragma unroll
      for (int qt2 = 0; qt2 < 4; ++qt2)
#pragma unroll
        for (int ks = 0; ks < 2; ++ks)
          qb[qt2][ks] = *(const half8*)(lsK + ks * 4096 +
                                        (lrow + qt2 * 16 + l15) * 32 + qsw8);
    }
    __syncthreads();
  }

  // ---- stage K(0), V(0) into buf 0: 512 slots each, 2/thread ----
#pragma unroll
  for (int i = 0; i < 2; ++i) {
    int c = i * 256 + tid;
    g2l16(Kb + ((c >> 2) & 63) * 64 + (c >> 8) * 32 + swz(c) * 8,
          lsK + (i * 256 + wave * 64) * 8);
    g2l16(Vb + ((c >> 2) & 63) * 2048 + (c >> 8) * 32 + swz(c) * 8,
          lsV + (i * 256 + wave * 64) * 8);
  }

  half8 onesf;
#pragma unroll
  for (int j = 0; j < 8; ++j) onesf[j] = (_Float16)1.0f;

  floatx4 oacc[4][4] = {};  // [qt2][dt]
  floatx4 osum[4] = {};     // row-sums l, oacc row layout (via ones-MFMA)

  for (int kt = 0; kt < 32; ++kt) {
    const int cur = kt & 1;
    const u16* bufK = lsK + cur * 4096;
    const u16* bufV = lsV + cur * 4096;
    __syncthreads();
    if (kt < 31) {
      u16* nK = lsK + (1 - cur) * 4096;
      u16* nV = lsV + (1 - cur) * 4096;
#pragma unroll
      for (int i = 0; i < 2; ++i) {
        int c = i * 256 + tid;
        g2l16(Kb + (kt + 1) * 4096 + ((c >> 2) & 63) * 64 + (c >> 8) * 32 + swz(c) * 8,
              nK + (i * 256 + wave * 64) * 8);
        g2l16(Vb + ((c >> 2) & 63) * 2048 + (kt + 1) * 64 + (c >> 8) * 32 + swz(c) * 8,
              nV + (i * 256 + wave * 64) * 8);
      }
    }
#pragma unroll
    for (int ks4 = 0; ks4 < 2; ++ks4) {
      // ---- S^T for this 32-key slab: k = ks4*32 + h*16 + quad*4+r ----
      floatx4 sacc[2][4] = {};  // [h][qt2]
      __builtin_amdgcn_s_setprio(1);
#pragma unroll
      for (int ks = 0; ks < 2; ++ks) {
#pragma unroll
        for (int h = 0; h < 2; ++h) {
          half8 kf = *(const half8*)(bufK + ks * 2048 + ((ks4 * 2 + h) * 16 + l15) * 32 + qsw8);
#pragma unroll
          for (int qt2 = 0; qt2 < 4; ++qt2)
            sacc[h][qt2] = __builtin_amdgcn_mfma_f32_16x16x32_f16(kf, qb[qt2][ks], sacc[h][qt2], 0, 0, 0);
        }
      }
      __builtin_amdgcn_s_setprio(0);
      // ---- P = exp2(s) (Q pre-scaled), packed write ----
#pragma unroll
      for (int h = 0; h < 2; ++h) {
#pragma unroll
        for (int qt2 = 0; qt2 < 4; ++qt2) {
          float p0 = __builtin_amdgcn_exp2f(sacc[h][qt2][0]);
          float p1 = __builtin_amdgcn_exp2f(sacc[h][qt2][1]);
          float p2 = __builtin_amdgcn_exp2f(sacc[h][qt2][2]);
          float p3 = __builtin_amdgcn_exp2f(sacc[h][qt2][3]);
          union { fp16v2 h2; unsigned u; } lo, hi;
          lo.h2 = __builtin_amdgcn_cvt_pkrtz(p0, p1);
          hi.h2 = __builtin_amdgcn_cvt_pkrtz(p2, p3);
          uint2 pk = {lo.u, hi.u};
          *(uint2*)(lsPw + (qt2 * 16 + l15) * 32 +
                    (((2 * h + (quad >> 1)) ^ sw) * 8) + (quad & 1) * 4) = pk;
        }
      }
      // ---- PV + ones-MFMA row-sum ----
      half8 pa[4];
#pragma unroll
      for (int qt2 = 0; qt2 < 4; ++qt2)
        pa[qt2] = *(const half8*)(lsPw + (qt2 * 16 + l15) * 32 + qsw8);
      __builtin_amdgcn_s_setprio(1);
#pragma unroll
      for (int dt = 0; dt < 4; ++dt) {
        half8 vb = *(const half8*)(bufV + ks4 * 2048 + (dt * 16 + l15) * 32 + qsw8);
#pragma unroll
        for (int qt2 = 0; qt2 < 4; ++qt2)
          oacc[qt2][dt] = __builtin_amdgcn_mfma_f32_16x16x32_f16(pa[qt2], vb, oacc[qt2][dt], 0, 0, 0);
      }
#pragma unroll
      for (int qt2 = 0; qt2 < 4; ++qt2)
        osum[qt2] = __builtin_amdgcn_mfma_f32_16x16x32_f16(pa[qt2], onesf, osum[qt2], 0, 0, 0);
      __builtin_amdgcn_s_setprio(0);
    }
  }

  // ---- epilogue: O / l -> fp16 attn_out[B, N, H*64] ----
  const int b = bh >> 4, h = bh & 15;
#pragma unroll
  for (int qt2 = 0; qt2 < 4; ++qt2) {
#pragma unroll
    for (int r = 0; r < 4; ++r) {
      float inv = 1.0f / osum[qt2][r];
      int qrow = qt * 256 + wave * 64 + qt2 * 16 + quad * 4 + r;
      long long rowbase = ((long long)b * 2048 + qrow) * 1024 + h * 64;
#pragma unroll
      for (int dt = 0; dt < 4; ++dt)
        Oh[rowbase + dt * 16 + l15] = f2h(oacc[qt2][dt][r] * inv);
    }
  }
}

// ---------------------------------------------------------------------------
extern "C" void kernel_launch(void* const* d_in, const int* in_sizes, int n_in,
                              void* d_out, int out_size, void* d_ws, size_t ws_size,
                              hipStream_t stream) {
  const float* x = (const float*)d_in[0];      // [4,2048,1024]
  const float* Wqkv = (const float*)d_in[1];   // [1024,3072]
  const float* Wout = (const float*)d_in[2];   // [1024,1024]
  const float* bout = (const float*)d_in[3];   // [1024]
  float* out = (float*)d_out;                  // [4,2048,1024] fp32

  char* ws = (char*)d_ws;  // 88 MB used
  u16* Xh = (u16*)(ws);                          // 16 MB  [8192,1024]
  u16* Wqkvt = (u16*)(ws + (16ll << 20));        //  6 MB  [3072,1024]
  u16* Woutt = (u16*)(ws + (22ll << 20));        //  2 MB  [1024,1024]
  u16* Qh = (u16*)(ws + (24ll << 20));           // 16 MB  [B,H,2048,64] (pre-scaled)
  u16* Kh = (u16*)(ws + (40ll << 20));           // 16 MB  [B,H,2048,64]
  u16* Vt = (u16*)(ws + (56ll << 20));           // 16 MB  [B,H,64,2048]
  u16* Oh = (u16*)(ws + (72ll << 20));           // 16 MB  [8192,1024]

  prep<<<5120, 256, 0, stream>>>(x, Xh, Wqkv, Wqkvt, Wout, Woutt);
  qkv_gemm<<<768, 256, 0, stream>>>(Xh, Wqkvt, Qh, Kh, Vt);
  attn_flash<<<512, 256, 0, stream>>>(Qh, Kh, Vt, Oh);
  out_gemm<<<512, 256, 0, stream>>>(Oh, Woutt, out, bout);
}

// Round 6
// 249.440 us; speedup vs baseline: 1.0755x; 1.0755x over previous
//
#include <hip/hip_runtime.h>

// ---------------------------------------------------------------------------
// Attention (B=4, N=2048, DIM=1024, H=16, Dh=64) in fp16 MFMA, fp32 accum.
// Pipeline: prep (cast + 2 transposes fused) -> gemm<0> (qkv, scatter epi)
//           -> flash attn -> gemm<1> (out proj + bias).
// R13: gemms reverted to R3/R11 bodies (128^2, 3-buf counted vmcnt, 3
//   blk/CU — R5 proved 128x64-wave-tile qkv is occupancy/register-bounded:
//   +22us). attn: slab-interleaved softmax pipeline. Per KT the two 32-key
//   slabs each get their OWN P buffer (lsP 16->32KB, LDS 64KB, still 2
//   blk/CU) and are interleaved QK0 -> exp0/P0 -> QK1 -> PV0 -> exp1/P1 ->
//   PV1, so each P LDS round-trip is covered by an independent MFMA cluster
//   (attn was dependency-chain bound: 5900 cyc/KT wall vs 2300 cyc work).
// ---------------------------------------------------------------------------

typedef _Float16 half8 __attribute__((ext_vector_type(8)));
typedef __fp16 fp16v2 __attribute__((ext_vector_type(2)));
typedef float floatx4 __attribute__((ext_vector_type(4)));
typedef unsigned short u16;

struct __align__(8) U16x4 { u16 x, y, z, w; };

__device__ __forceinline__ u16 f2h(float f) {
  union { _Float16 h; u16 u; } cv;
  cv.h = (_Float16)f;
  return cv.u;
}

// async global->LDS, 16B per lane. LDS dest = wave-uniform base + lane*16.
__device__ __forceinline__ void g2l16(const void* g, void* l) {
  __builtin_amdgcn_global_load_lds(
      (const __attribute__((address_space(1))) void*)g,
      (__attribute__((address_space(3))) void*)l, 16, 0, 0);
}

// 2-bit chunk swizzle (4 chunks/row): slot c, row=c>>2 -> chunk^((row>>1)&3)
__device__ __forceinline__ int swz(int c) { return (c & 3) ^ ((c >> 3) & 3); }

// ---------------------------------------------------------------------------
// Kernel 1: fused prep. Blocks [0,4096): flat cast x fp32->fp16.
// Blocks [4096,4864): transpose+cast Wqkv [1024][3072] -> [3072][1024].
// Blocks [4864,5120): transpose+cast Wout [1024][1024] -> [1024][1024].
// ---------------------------------------------------------------------------
__global__ __launch_bounds__(256) void prep(const float* __restrict__ x,
                                            u16* __restrict__ Xh,
                                            const float* __restrict__ Wqkv,
                                            u16* __restrict__ Wqkvt,
                                            const float* __restrict__ Wout,
                                            u16* __restrict__ Woutt) {
  __shared__ u16 ls[64][72];
  const int bid = blockIdx.x;
  const int tid = threadIdx.x;
  if (bid < 4096) {
    long long base = ((long long)bid * 256 + tid) * 8;
    float4 a = *(const float4*)(x + base);
    float4 b = *(const float4*)(x + base + 4);
    U16x4 u0 = {f2h(a.x), f2h(a.y), f2h(a.z), f2h(a.w)};
    U16x4 u1 = {f2h(b.x), f2h(b.y), f2h(b.z), f2h(b.w)};
    *(U16x4*)(Xh + base) = u0;
    *(U16x4*)(Xh + base + 4) = u1;
    return;
  }
  const float* in;
  u16* out;
  int N, tile;
  if (bid < 4096 + 768) { in = Wqkv; out = Wqkvt; N = 3072; tile = bid - 4096; }
  else                  { in = Wout; out = Woutt; N = 1024; tile = bid - 4864; }
  const int K = 1024, nTK = 16;
  const int tk = tile % nTK, tn = tile / nTK;
#pragma unroll
  for (int i = 0; i < 4; ++i) {
    int idx = i * 256 + tid;
    int r = idx >> 4, c4 = (idx & 15) * 4;
    float4 v = *(const float4*)(in + (long long)(tk * 64 + r) * N + tn * 64 + c4);
    ls[r][c4 + 0] = f2h(v.x);
    ls[r][c4 + 1] = f2h(v.y);
    ls[r][c4 + 2] = f2h(v.z);
    ls[r][c4 + 3] = f2h(v.w);
  }
  __syncthreads();
#pragma unroll
  for (int i = 0; i < 4; ++i) {
    int idx = i * 256 + tid;
    int nr = idx >> 4, kc4 = (idx & 15) * 4;
    U16x4 u = {ls[kc4 + 0][nr], ls[kc4 + 1][nr], ls[kc4 + 2][nr], ls[kc4 + 3][nr]};
    *(U16x4*)(out + (long long)(tn * 64 + nr) * K + tk * 64 + kc4) = u;
  }
}

// ---------------------------------------------------------------------------
// Kernel 2/4: fp16 GEMM, C[M,N] = A[M,1024] @ Bt[N,1024]^T (R3/R11 body).
//   128x128 tile, BK=32, 32 KT, 256 thr / 4 waves (wave tile 64x64).
//   3 LDS buffers (48KB -> 3 blocks/CU). Per KT t: 8x ds_read_b128 (XOR
//   chunk swizzle); stage KT t+2 into buf (cur+2)%3; s_barrier; lgkm(0);
//   16 MFMA; vmcnt(4) [t<30] / vmcnt(0) [t==30]; s_barrier.
//   EPI=0: scatter Q (pre-scaled), K, V^T.  EPI=1: fp32 + bias.
// ---------------------------------------------------------------------------
template <int EPI>
__global__ __launch_bounds__(256, 3) void gemm_f16(const u16* __restrict__ A,
                                                   const u16* __restrict__ Bt,
                                                   u16* __restrict__ O0,
                                                   u16* __restrict__ O1,
                                                   u16* __restrict__ O2,
                                                   float* __restrict__ Of,
                                                   const float* __restrict__ bias) {
  __shared__ __attribute__((aligned(16))) u16 lsA[3 * 4096];  // 24KB
  __shared__ __attribute__((aligned(16))) u16 lsB[3 * 4096];  // 24KB
  const int tid = threadIdx.x;
  const int lane = tid & 63, wave = tid >> 6;
  const int l15 = lane & 15, quad = lane >> 4;
  const int rdoff = (quad ^ ((l15 >> 1) & 3)) * 8;  // read-side chunk swizzle
  const int wm = (wave >> 1) * 64, wn = (wave & 1) * 64;
  const int bm = blockIdx.x & 63, bn = blockIdx.x >> 6;

  // staging: slot sl = j*256+tid covers (row r, chunk cc) of an 8KB K-tile;
  // source chunk pre-swizzled so linear LDS write + swizzled read match.
  const u16* gA[2];
  const u16* gB[2];
  int dst[2];
#pragma unroll
  for (int j = 0; j < 2; ++j) {
    int sl = j * 256 + tid;
    int r = sl >> 2, cc = sl & 3;
    int csw = (cc ^ ((r >> 1) & 3)) * 8;
    gA[j] = A + (long long)(bm * 128 + r) * 1024 + csw;
    gB[j] = Bt + (long long)(bn * 128 + r) * 1024 + csw;
    dst[j] = sl * 8;  // u16 units; byte = sl*16 = uniform + lane*16
  }

  floatx4 acc[4][4] = {};

  // ---- prologue: stage KT0 -> buf0, KT1 -> buf1 (8 loads/thread) ----
#pragma unroll
  for (int t = 0; t < 2; ++t) {
#pragma unroll
    for (int j = 0; j < 2; ++j) g2l16(gA[j] + t * 32, lsA + t * 4096 + dst[j]);
#pragma unroll
    for (int j = 0; j < 2; ++j) g2l16(gB[j] + t * 32, lsB + t * 4096 + dst[j]);
  }
  asm volatile("s_waitcnt vmcnt(4)");  // KT0 landed; KT1 in flight
  __builtin_amdgcn_s_barrier();

  int cur = 0;
  for (int t = 0; t < 32; ++t) {
    const u16* bA = lsA + cur * 4096;
    const u16* bB = lsB + cur * 4096;
    half8 af[4], bf[4];
#pragma unroll
    for (int i = 0; i < 4; ++i)
      af[i] = *(const half8*)(bA + (wm + i * 16 + l15) * 32 + rdoff);
#pragma unroll
    for (int i = 0; i < 4; ++i)
      bf[i] = *(const half8*)(bB + (wn + i * 16 + l15) * 32 + rdoff);
    if (t < 30) {  // stage KT t+2 into buf (cur+2)%3 (its readers finished at t-1)
      const int nb = cur ? cur - 1 : 2;
      const int ko = (t + 2) * 32;
#pragma unroll
      for (int j = 0; j < 2; ++j) g2l16(gA[j] + ko, lsA + nb * 4096 + dst[j]);
#pragma unroll
      for (int j = 0; j < 2; ++j) g2l16(gB[j] + ko, lsB + nb * 4096 + dst[j]);
    }
    __builtin_amdgcn_s_barrier();
    asm volatile("s_waitcnt lgkmcnt(0)");
#pragma unroll
    for (int mt = 0; mt < 4; ++mt)
#pragma unroll
      for (int nt = 0; nt < 4; ++nt)
        acc[mt][nt] = __builtin_amdgcn_mfma_f32_16x16x32_f16(af[mt], bf[nt],
                                                             acc[mt][nt], 0, 0, 0);
    if (t < 30)       asm volatile("s_waitcnt vmcnt(4)");  // KT t+1 landed
    else if (t == 30) asm volatile("s_waitcnt vmcnt(0)");  // KT31 landed
    __builtin_amdgcn_s_barrier();
    cur = cur == 2 ? 0 : cur + 1;
  }

  if (EPI == 0) {
    const float slq = 0.125f * 1.44269504088896f;  // SCALE*log2(e), folded into Q
#pragma unroll
    for (int mt = 0; mt < 4; ++mt) {
      int gm = bm * 128 + wm + mt * 16 + quad * 4;
      int b = gm >> 11, n0 = gm & 2047;
#pragma unroll
      for (int nt = 0; nt < 4; ++nt) {
        int gc = bn * 128 + wn + nt * 16 + l15;
        int tsel = gc >> 10, hd = gc & 1023, h = hd >> 6, d = hd & 63;
        long long bh = (long long)(b * 16 + h);
        if (tsel == 2) {
          U16x4 u = {f2h(acc[mt][nt][0]), f2h(acc[mt][nt][1]),
                     f2h(acc[mt][nt][2]), f2h(acc[mt][nt][3])};
          *(U16x4*)(O2 + (bh * 64 + d) * 2048 + n0) = u;
        } else {
          float s = (tsel == 0) ? slq : 1.0f;
          u16* dstp = (tsel == 0 ? O0 : O1) + (bh * 2048 + n0) * 64 + d;
#pragma unroll
          for (int r = 0; r < 4; ++r) dstp[r * 64] = f2h(acc[mt][nt][r] * s);
        }
      }
    }
  } else {
#pragma unroll
    for (int mt = 0; mt < 4; ++mt) {
      int gm = bm * 128 + wm + mt * 16 + quad * 4;
#pragma unroll
      for (int nt = 0; nt < 4; ++nt) {
        int gc = bn * 128 + wn + nt * 16 + l15;
        float bv = bias[gc];
#pragma unroll
        for (int r = 0; r < 4; ++r)
          Of[(long long)(gm + r) * 1024 + gc] = acc[mt][nt][r] + bv;
      }
    }
  }
}

// ---------------------------------------------------------------------------
// Kernel 3: flash attention, slab-interleaved. Wave owns 64 q, q-tile
// 256/block, grid 512. Double-buffered 64-key K/V tiles, one barrier/iter,
// S^T formulation, no-shift softmax (Q pre-scaled), MFMA row-sums.
// R13: per-KT the two 32-key slabs get separate P buffers and interleave
//   QK0 -> exp0/P0 -> QK1 -> PV0 -> exp1/P1 -> PV1 (each P LDS round-trip
//   covered by an independent MFMA cluster). LDS 16+16+32 = 64KB, 2 blk/CU.
// ---------------------------------------------------------------------------
__global__ __launch_bounds__(256, 2) void attn_flash(const u16* __restrict__ Qh,
                                                     const u16* __restrict__ Kh,
                                                     const u16* __restrict__ Vt,
                                                     u16* __restrict__ Oh) {
  __shared__ __attribute__((aligned(16))) u16 lsK[2 * 2 * 64 * 32];   // 16KB
  __shared__ __attribute__((aligned(16))) u16 lsV[2 * 2 * 64 * 32];   // 16KB
  __shared__ __attribute__((aligned(16))) u16 lsP[4 * 2 * 64 * 32];   // 32KB
  const int tid = threadIdx.x;
  const int lane = tid & 63, wave = tid >> 6;
  const int l15 = lane & 15, quad = lane >> 4;
  const int sw = (l15 >> 1) & 3;
  const int qsw8 = (quad ^ sw) * 8;
  const int bh = blockIdx.x & 63, qt = blockIdx.x >> 6;  // qt in [0,8)
  const u16* Qb = Qh + ((long long)bh * 2048 + qt * 256) * 64;
  const u16* Kb = Kh + (long long)bh * 2048 * 64;
  const u16* Vb = Vt + (long long)bh * 64 * 2048;
  u16* lsPw = lsP + wave * 4096;  // [2 slab][64][32]

  // ---- stage Q in two 128-row passes via lsK [2 dslab][128 row][32] ----
  half8 qb[4][2];  // [qt2][dslab]
#pragma unroll
  for (int pass = 0; pass < 2; ++pass) {
#pragma unroll
    for (int i = 0; i < 4; ++i) {
      int c = i * 256 + tid;
      g2l16(Qb + (pass * 128 + ((c >> 2) & 127)) * 64 + (c >> 9) * 32 + swz(c) * 8,
            lsK + (i * 256 + wave * 64) * 8);
    }
    __syncthreads();
    if ((wave >> 1) == pass) {
      const int lrow = (wave & 1) * 64;
#pragma unroll
      for (int qt2 = 0; qt2 < 4; ++qt2)
#pragma unroll
        for (int ks = 0; ks < 2; ++ks)
          qb[qt2][ks] = *(const half8*)(lsK + ks * 4096 +
                                        (lrow + qt2 * 16 + l15) * 32 + qsw8);
    }
    __syncthreads();
  }

  // ---- stage K(0), V(0) into buf 0: 512 slots each, 2/thread ----
#pragma unroll
  for (int i = 0; i < 2; ++i) {
    int c = i * 256 + tid;
    g2l16(Kb + ((c >> 2) & 63) * 64 + (c >> 8) * 32 + swz(c) * 8,
          lsK + (i * 256 + wave * 64) * 8);
    g2l16(Vb + ((c >> 2) & 63) * 2048 + (c >> 8) * 32 + swz(c) * 8,
          lsV + (i * 256 + wave * 64) * 8);
  }

  half8 onesf;
#pragma unroll
  for (int j = 0; j < 8; ++j) onesf[j] = (_Float16)1.0f;

  floatx4 oacc[4][4] = {};  // [qt2][dt]
  floatx4 osum[4] = {};     // row-sums l, oacc row layout (via ones-MFMA)

  for (int kt = 0; kt < 32; ++kt) {
    const int cur = kt & 1;
    const u16* bufK = lsK + cur * 4096;
    const u16* bufV = lsV + cur * 4096;
    __syncthreads();
    if (kt < 31) {
      u16* nK = lsK + (1 - cur) * 4096;
      u16* nV = lsV + (1 - cur) * 4096;
#pragma unroll
      for (int i = 0; i < 2; ++i) {
        int c = i * 256 + tid;
        g2l16(Kb + (kt + 1) * 4096 + ((c >> 2) & 63) * 64 + (c >> 8) * 32 + swz(c) * 8,
              nK + (i * 256 + wave * 64) * 8);
        g2l16(Vb + ((c >> 2) & 63) * 2048 + (kt + 1) * 64 + (c >> 8) * 32 + swz(c) * 8,
              nV + (i * 256 + wave * 64) * 8);
      }
    }

    // ======== QK slab0 (keys 0..31 of this KT) ========
    floatx4 sacc0[2][4] = {};  // [h][qt2]
    __builtin_amdgcn_s_setprio(1);
#pragma unroll
    for (int ks = 0; ks < 2; ++ks) {
#pragma unroll
      for (int h = 0; h < 2; ++h) {
        half8 kf = *(const half8*)(bufK + ks * 2048 + (h * 16 + l15) * 32 + qsw8);
#pragma unroll
        for (int qt2 = 0; qt2 < 4; ++qt2)
          sacc0[h][qt2] = __builtin_amdgcn_mfma_f32_16x16x32_f16(kf, qb[qt2][ks], sacc0[h][qt2], 0, 0, 0);
      }
    }
    __builtin_amdgcn_s_setprio(0);

    // ======== exp/pack slab0 -> P0 ========
#pragma unroll
    for (int h = 0; h < 2; ++h) {
#pragma unroll
      for (int qt2 = 0; qt2 < 4; ++qt2) {
        float p0 = __builtin_amdgcn_exp2f(sacc0[h][qt2][0]);
        float p1 = __builtin_amdgcn_exp2f(sacc0[h][qt2][1]);
        float p2 = __builtin_amdgcn_exp2f(sacc0[h][qt2][2]);
        float p3 = __builtin_amdgcn_exp2f(sacc0[h][qt2][3]);
        union { fp16v2 h2; unsigned u; } lo, hi;
        lo.h2 = __builtin_amdgcn_cvt_pkrtz(p0, p1);
        hi.h2 = __builtin_amdgcn_cvt_pkrtz(p2, p3);
        uint2 pk = {lo.u, hi.u};
        *(uint2*)(lsPw + (qt2 * 16 + l15) * 32 +
                  (((2 * h + (quad >> 1)) ^ sw) * 8) + (quad & 1) * 4) = pk;
      }
    }

    // ======== QK slab1 (keys 32..63) — covers P0 round-trip ========
    floatx4 sacc1[2][4] = {};
    __builtin_amdgcn_s_setprio(1);
#pragma unroll
    for (int ks = 0; ks < 2; ++ks) {
#pragma unroll
      for (int h = 0; h < 2; ++h) {
        half8 kf = *(const half8*)(bufK + ks * 2048 + ((2 + h) * 16 + l15) * 32 + qsw8);
#pragma unroll
        for (int qt2 = 0; qt2 < 4; ++qt2)
          sacc1[h][qt2] = __builtin_amdgcn_mfma_f32_16x16x32_f16(kf, qb[qt2][ks], sacc1[h][qt2], 0, 0, 0);
      }
    }
    __builtin_amdgcn_s_setprio(0);

    // ======== PV slab0 ========
    {
      half8 pa[4];
#pragma unroll
      for (int qt2 = 0; qt2 < 4; ++qt2)
        pa[qt2] = *(const half8*)(lsPw + (qt2 * 16 + l15) * 32 + qsw8);
      __builtin_amdgcn_s_setprio(1);
#pragma unroll
      for (int dt = 0; dt < 4; ++dt) {
        half8 vb = *(const half8*)(bufV + (dt * 16 + l15) * 32 + qsw8);
#pragma unroll
        for (int qt2 = 0; qt2 < 4; ++qt2)
          oacc[qt2][dt] = __builtin_amdgcn_mfma_f32_16x16x32_f16(pa[qt2], vb, oacc[qt2][dt], 0, 0, 0);
      }
#pragma unroll
      for (int qt2 = 0; qt2 < 4; ++qt2)
        osum[qt2] = __builtin_amdgcn_mfma_f32_16x16x32_f16(pa[qt2], onesf, osum[qt2], 0, 0, 0);
      __builtin_amdgcn_s_setprio(0);
    }

    // ======== exp/pack slab1 -> P1 ========
#pragma unroll
    for (int h = 0; h < 2; ++h) {
#pragma unroll
      for (int qt2 = 0; qt2 < 4; ++qt2) {
        float p0 = __builtin_amdgcn_exp2f(sacc1[h][qt2][0]);
        float p1 = __builtin_amdgcn_exp2f(sacc1[h][qt2][1]);
        float p2 = __builtin_amdgcn_exp2f(sacc1[h][qt2][2]);
        float p3 = __builtin_amdgcn_exp2f(sacc1[h][qt2][3]);
        union { fp16v2 h2; unsigned u; } lo, hi;
        lo.h2 = __builtin_amdgcn_cvt_pkrtz(p0, p1);
        hi.h2 = __builtin_amdgcn_cvt_pkrtz(p2, p3);
        uint2 pk = {lo.u, hi.u};
        *(uint2*)(lsPw + 2048 + (qt2 * 16 + l15) * 32 +
                  (((2 * h + (quad >> 1)) ^ sw) * 8) + (quad & 1) * 4) = pk;
      }
    }

    // ======== PV slab1 ========
    {
      half8 pa[4];
#pragma unroll
      for (int qt2 = 0; qt2 < 4; ++qt2)
        pa[qt2] = *(const half8*)(lsPw + 2048 + (qt2 * 16 + l15) * 32 + qsw8);
      __builtin_amdgcn_s_setprio(1);
#pragma unroll
      for (int dt = 0; dt < 4; ++dt) {
        half8 vb = *(const half8*)(bufV + 2048 + (dt * 16 + l15) * 32 + qsw8);
#pragma unroll
        for (int qt2 = 0; qt2 < 4; ++qt2)
          oacc[qt2][dt] = __builtin_amdgcn_mfma_f32_16x16x32_f16(pa[qt2], vb, oacc[qt2][dt], 0, 0, 0);
      }
#pragma unroll
      for (int qt2 = 0; qt2 < 4; ++qt2)
        osum[qt2] = __builtin_amdgcn_mfma_f32_16x16x32_f16(pa[qt2], onesf, osum[qt2], 0, 0, 0);
      __builtin_amdgcn_s_setprio(0);
    }
  }

  // ---- epilogue: O / l -> fp16 attn_out[B, N, H*64] ----
  const int b = bh >> 4, h = bh & 15;
#pragma unroll
  for (int qt2 = 0; qt2 < 4; ++qt2) {
#pragma unroll
    for (int r = 0; r < 4; ++r) {
      float inv = 1.0f / osum[qt2][r];
      int qrow = qt * 256 + wave * 64 + qt2 * 16 + quad * 4 + r;
      long long rowbase = ((long long)b * 2048 + qrow) * 1024 + h * 64;
#pragma unroll
      for (int dt = 0; dt < 4; ++dt)
        Oh[rowbase + dt * 16 + l15] = f2h(oacc[qt2][dt][r] * inv);
    }
  }
}

// ---------------------------------------------------------------------------
extern "C" void kernel_launch(void* const* d_in, const int* in_sizes, int n_in,
                              void* d_out, int out_size, void* d_ws, size_t ws_size,
                              hipStream_t stream) {
  const float* x = (const float*)d_in[0];      // [4,2048,1024]
  const float* Wqkv = (const float*)d_in[1];   // [1024,3072]
  const float* Wout = (const float*)d_in[2];   // [1024,1024]
  const float* bout = (const float*)d_in[3];   // [1024]
  float* out = (float*)d_out;                  // [4,2048,1024] fp32

  char* ws = (char*)d_ws;  // 88 MB used
  u16* Xh = (u16*)(ws);                          // 16 MB  [8192,1024]
  u16* Wqkvt = (u16*)(ws + (16ll << 20));        //  6 MB  [3072,1024]
  u16* Woutt = (u16*)(ws + (22ll << 20));        //  2 MB  [1024,1024]
  u16* Qh = (u16*)(ws + (24ll << 20));           // 16 MB  [B,H,2048,64] (pre-scaled)
  u16* Kh = (u16*)(ws + (40ll << 20));           // 16 MB  [B,H,2048,64]
  u16* Vt = (u16*)(ws + (56ll << 20));           // 16 MB  [B,H,64,2048]
  u16* Oh = (u16*)(ws + (72ll << 20));           // 16 MB  [8192,1024]

  prep<<<5120, 256, 0, stream>>>(x, Xh, Wqkv, Wqkvt, Wout, Woutt);
  gemm_f16<0><<<1536, 256, 0, stream>>>(Xh, Wqkvt, Qh, Kh, Vt, nullptr, nullptr);
  attn_flash<<<512, 256, 0, stream>>>(Qh, Kh, Vt, Oh);
  gemm_f16<1><<<512, 256, 0, stream>>>(Oh, Woutt, nullptr, nullptr, nullptr, out, bout);
}